// Round 4
// baseline (3453.951 us; speedup 1.0000x reference)
//
#include <hip/hip_runtime.h>

#define NPTS 256
#define NBATCH 64
#define BIGF 1e30f

__device__ __forceinline__ float rlane(float v, int l) {
    return __uint_as_float((unsigned int)__builtin_amdgcn_readlane((int)__float_as_uint(v), l));
}
__device__ __forceinline__ int rlanei(int v, int l) {
    return __builtin_amdgcn_readlane(v, l);
}

// Uniform-slot select over a 4-register array (slot is wave-uniform).
#define SEL4(a, s) ((s) == 0 ? a[0] : (s) == 1 ? a[1] : (s) == 2 ? a[2] : a[3])

// One DPP step: combine v with dpp-shuffled v; invalid lanes keep old v.
#define DPP_FMIN(v, ctrl) \
    fminf(v, __int_as_float(__builtin_amdgcn_update_dpp( \
        __float_as_int(v), __float_as_int(v), (ctrl), 0xf, 0xf, false)))
#define DPP_UMIN(v, ctrl) \
    (min)((v), (unsigned int)__builtin_amdgcn_update_dpp( \
        (int)(v), (int)(v), (ctrl), 0xf, 0xf, false))

// Full-wave fmin, broadcast via lane 63 readlane (uniform result).
__device__ __forceinline__ float wave_fmin_bcast(float v) {
    v = DPP_FMIN(v, 0x111);   // row_shr:1
    v = DPP_FMIN(v, 0x112);   // row_shr:2
    v = DPP_FMIN(v, 0x114);   // row_shr:4
    v = DPP_FMIN(v, 0x118);   // row_shr:8
    v = DPP_FMIN(v, 0x142);   // row_bcast:15
    v = DPP_FMIN(v, 0x143);   // row_bcast:31
    return rlane(v, 63);
}
// Full-wave u32 min, result read from lane 63 (uniform).
__device__ __forceinline__ unsigned int wave_umin_bcast(unsigned int v) {
    v = DPP_UMIN(v, 0x111);
    v = DPP_UMIN(v, 0x112);
    v = DPP_UMIN(v, 0x114);
    v = DPP_UMIN(v, 0x118);
    v = DPP_UMIN(v, 0x142);
    v = DPP_UMIN(v, 0x143);
    return (unsigned int)rlanei((int)v, 63);
}

__global__ void zero_out_kernel(float* out, int n) {
    int i = blockIdx.x * blockDim.x + threadIdx.x;
    if (i < n) out[i] = 0.0f;
}

// One wave per batch. Lane owns columns/rows {lane, 64+lane, 128+lane, 192+lane}.
// JV: column reduction -> greedy claim -> augmenting row reduction (ARR) ->
// delta-accumulated Dijkstra for leftovers. All register-resident, no LDS/barriers.
__launch_bounds__(64, 1)
__global__ void hungarian_wave(const float* __restrict__ pred,
                               const float* __restrict__ target,
                               float* __restrict__ out) {
    const int b    = blockIdx.x;
    const int lane = threadIdx.x;

    const float* pb = pred   + (size_t)b * NPTS * 3;
    const float* tb = target + (size_t)b * NPTS * 3;

    float prx[4], pry[4], prz[4];      // pred (row) points, row = c*64+lane
    float tx[4], ty[4], tz[4];         // target (col) points, col = c*64+lane
    float vv[4], upc[4], Mv[4];
    int   pc[4]  = {-1, -1, -1, -1};   // matched row per column (-1 = free)
    int   way[4];

#pragma unroll
    for (int c = 0; c < 4; ++c) {
        int idx = c * 64 + lane;
        prx[c] = pb[idx * 3 + 0]; pry[c] = pb[idx * 3 + 1]; prz[c] = pb[idx * 3 + 2];
        tx[c]  = tb[idx * 3 + 0]; ty[c]  = tb[idx * 3 + 1]; tz[c]  = tb[idx * 3 + 2];
        upc[c] = 0.f;
    }

    // ---- Phase 1a: column reduction. vv[c] = min_r d(r, col), colrow = argmin ----
    float colmin[4] = {BIGF, BIGF, BIGF, BIGF};
    int   colrow[4] = {0, 0, 0, 0};
#pragma unroll
    for (int rs = 0; rs < 4; ++rs) {
        for (int rl = 0; rl < 64; ++rl) {
            float bx = rlane(prx[rs], rl), by = rlane(pry[rs], rl), bz = rlane(prz[rs], rl);
            int r = rs * 64 + rl;
#pragma unroll
            for (int c = 0; c < 4; ++c) {
                float dx = bx - tx[c], dy = by - ty[c], dz = bz - tz[c];
                float d = sqrtf(dx * dx + dy * dy + dz * dz);
                if (d < colmin[c]) { colmin[c] = d; colrow[c] = r; }
            }
        }
    }
#pragma unroll
    for (int c = 0; c < 4; ++c) vv[c] = colmin[c];

    // ---- Phase 1b: greedy claim — column (ascending) claims its argmin row if free ----
    unsigned long long frm[4];         // free-row masks (wave-uniform dataflow)
    frm[0] = frm[1] = frm[2] = frm[3] = ~0ull;
#pragma unroll
    for (int cs = 0; cs < 4; ++cs) {
        for (int l = 0; l < 64; ++l) {
            int r = rlanei(colrow[cs], l);
            int rs = r >> 6, rl2 = r & 63;
            unsigned long long bit = 1ull << rl2;
            bool free_row = (SEL4(frm, rs) & bit) != 0ull;
#pragma unroll
            for (int s = 0; s < 4; ++s)
                if (s == rs && free_row) frm[s] &= ~bit;
            if (free_row && lane == l) { pc[cs] = r; upc[cs] = 0.f; }
        }
    }

    // ---- Phase 1c: augmenting row reduction (ARR) ----
    // For free row i: mu1 = min_j (d - v), j1 = argmin (exact); mu2 = 2nd min.
    // Set u[i] = mu2, v[j1] -= (mu2 - mu1), steal j1. Displaced row re-enters pool.
    // Zero-progress steals (mu2 == mu1 on occupied col) are deferred to phase 2.
    unsigned long long dfm[4] = {0ull, 0ull, 0ull, 0ull};
    {
        int budget = 1024;
        while ((frm[0] | frm[1] | frm[2] | frm[3]) != 0ull && budget-- > 0) {
            const int is = frm[0] ? 0 : frm[1] ? 1 : frm[2] ? 2 : 3;
            const unsigned long long mm = SEL4(frm, is);
            const int il = (int)__builtin_ctzll(mm);
#pragma unroll
            for (int s = 0; s < 4; ++s)
                if (s == is) frm[s] = mm & (mm - 1);
            const int i = is * 64 + il;

            const float bx = rlane(SEL4(prx, is), il);
            const float by = rlane(SEL4(pry, is), il);
            const float bz = rlane(SEL4(prz, is), il);

            float r[4]; float lval = BIGF; int lcol = 0;
#pragma unroll
            for (int c = 0; c < 4; ++c) {
                float dx = bx - tx[c], dy = by - ty[c], dz = bz - tz[c];
                float d = sqrtf(dx * dx + dy * dy + dz * dz);
                r[c] = d - vv[c];
                if (r[c] < lval) { lval = r[c]; lcol = c * 64 + lane; }
            }
            const float mu1 = wave_fmin_bcast(lval);         // exact min
            unsigned long long msk = __ballot(lval == mu1);
            const int fl = (int)__builtin_ctzll(msk);
            const int j1 = rlanei(lcol, fl);                 // exact argmin col
            const int osl = j1 >> 6, oln = j1 & 63;

            float lval2 = BIGF;                              // 2nd min (exclude j1)
#pragma unroll
            for (int c = 0; c < 4; ++c) {
                float e = (c * 64 + lane == j1) ? BIGF : r[c];
                lval2 = fminf(lval2, e);
            }
            const float mu2 = wave_fmin_bcast(lval2);
            const float amt = mu2 - mu1;                     // >= 0 exact

            const int pj1 = rlanei(SEL4(pc, osl), oln);
            if (pj1 >= 0 && !(amt > 0.f)) {                  // no progress possible: defer
#pragma unroll
                for (int s = 0; s < 4; ++s)
                    if (s == is) dfm[s] |= (1ull << il);
                continue;
            }
#pragma unroll
            for (int c = 0; c < 4; ++c)
                if (c == osl && lane == oln) { vv[c] -= amt; pc[c] = i; upc[c] = mu2; }
            if (pj1 >= 0) {
                const int ps = pj1 >> 6;
                const unsigned long long pbit = 1ull << (pj1 & 63);
#pragma unroll
                for (int s = 0; s < 4; ++s)
                    if (s == ps) frm[s] |= pbit;
            }
        }
    }

    // ---- Phase 2: Dijkstra shortest-path for remaining free rows ----
    float D = 0.f;
#pragma unroll
    for (int is = 0; is < 4; ++is) {
        unsigned long long m = frm[is] | dfm[is];
        while (m) {
            const int il = (int)__builtin_ctzll(m);
            m &= (m - 1);
            const int i = is * 64 + il;

#pragma unroll
            for (int c = 0; c < 4; ++c) Mv[c] = BIGF;
            int usedm = 0;

            int curi = i;          // current tree-expansion row
            float ukey = 0.f;      // u[i0] - D_at_entry
            int j0 = -1;
            int jfin = 0;

            while (true) {
                const int rs = curi >> 6, rl = curi & 63;
                const float bx = rlane(SEL4(prx, rs), rl);
                const float by = rlane(SEL4(pry, rs), rl);
                const float bz = rlane(SEL4(prz, rs), rl);

                // Slack update + packed (value|col) local min over free columns
                unsigned int kmin = 0xFFFFFFFFu;
#pragma unroll
                for (int c = 0; c < 4; ++c) {
                    const bool fr = !((usedm >> c) & 1);
                    float dx = bx - tx[c], dy = by - ty[c], dz = bz - tz[c];
                    float d = sqrtf(dx * dx + dy * dy + dz * dz);
                    float cand = d - ukey - vv[c];
                    if (fr && cand < Mv[c]) { Mv[c] = cand; way[c] = j0; }
                    unsigned int key = fr ? ((__float_as_uint(Mv[c]) & 0xFFFFFF00u)
                                             | (unsigned int)(c * 64 + lane))
                                          : 0xFFFFFFFFu;
                    kmin = (min)(kmin, key);
                }
                const unsigned int kk = wave_umin_bcast(kmin);   // single chain: min+argmin
                const int j1 = (int)(kk & 0xFFu);
                const int osl = j1 >> 6, oln = j1 & 63;

                const float gmin = rlane(SEL4(Mv, osl), oln);    // exact value for duals
                const int   pj   = rlanei(SEL4(pc, osl), oln);
                if (pj < 0) { jfin = j1; D = gmin; break; }
                const float uj = rlane(SEL4(upc, osl), oln);

                // Mark used; deferred-dual trick: +gmin now, net (D - gmin) at commit
#pragma unroll
                for (int c = 0; c < 4; ++c)
                    if (c == osl && lane == oln) {
                        usedm |= (1 << c);
                        vv[c] += gmin;
                        upc[c] -= gmin;
                    }

                curi = pj;
                ukey = uj - gmin;
                j0 = j1;
            }

            // Commit duals for tree columns: net amount = D_final - D_at_use
#pragma unroll
            for (int c = 0; c < 4; ++c)
                if ((usedm >> c) & 1) { vv[c] -= D; upc[c] += D; }

            // Augment along alternating path
            int jc = jfin;
            while (true) {
                const int osl = jc >> 6, oln = jc & 63;
                const int jw = rlanei(SEL4(way, osl), oln);
                int np_; float nup;
                if (jw < 0) { np_ = i; nup = D; }
                else {
                    const int wsl = jw >> 6, wln = jw & 63;
                    np_ = rlanei(SEL4(pc, wsl), wln);
                    nup = rlane(SEL4(upc, wsl), wln);
                }
#pragma unroll
                for (int c = 0; c < 4; ++c)
                    if (c == osl && lane == oln) { pc[c] = np_; upc[c] = nup; }
                if (jw < 0) break;
                jc = jw;
            }
        }
    }

    // ---- Matched cost: gather matched-row coords via shfl (per-lane row index) ----
    float s = 0.f;
#pragma unroll
    for (int c = 0; c < 4; ++c) {
        const int r = pc[c];
        const int rs = r >> 6, rl = r & 63;
        float cx[4], cy[4], cz[4];
#pragma unroll
        for (int q = 0; q < 4; ++q) {
            cx[q] = __shfl(prx[q], rl, 64);
            cy[q] = __shfl(pry[q], rl, 64);
            cz[q] = __shfl(prz[q], rl, 64);
        }
        const float px = SEL4(cx, rs), py = SEL4(cy, rs), pz = SEL4(cz, rs);
        float dx = px - tx[c], dy = py - ty[c], dz = pz - tz[c];
        s += sqrtf(dx * dx + dy * dy + dz * dz);
    }
#pragma unroll
    for (int off = 1; off < 64; off <<= 1) s += __shfl_xor(s, off, 64);
    if (lane == 0) atomicAdd(out, s / (float)NBATCH);
}

extern "C" void kernel_launch(void* const* d_in, const int* in_sizes, int n_in,
                              void* d_out, int out_size, void* d_ws, size_t ws_size,
                              hipStream_t stream) {
    const float* pred   = (const float*)d_in[0];
    const float* target = (const float*)d_in[1];
    float* out = (float*)d_out;

    zero_out_kernel<<<1, 64, 0, stream>>>(out, out_size);
    hungarian_wave<<<NBATCH, 64, 0, stream>>>(pred, target, out);
}

// Round 5
// 2076.336 us; speedup vs baseline: 1.6635x; 1.6635x over previous
//
#include <hip/hip_runtime.h>

#define NPTS 256
#define NBATCH 64
#define BIGF 1e30f

__device__ __forceinline__ float rlane(float v, int l) {
    return __uint_as_float((unsigned int)__builtin_amdgcn_readlane((int)__float_as_uint(v), l));
}
__device__ __forceinline__ int rlanei(int v, int l) {
    return __builtin_amdgcn_readlane(v, l);
}
__device__ __forceinline__ float rawsqrt(float x) {
    return __builtin_amdgcn_sqrtf(x);
}

// Uniform-slot select (slot wave-uniform); used only in cold paths.
#define SEL4(a, s) ((s) == 0 ? a[0] : (s) == 1 ? a[1] : (s) == 2 ? a[2] : a[3])

#define DPP_UMIN(v, ctrl) \
    (min)((v), (unsigned int)__builtin_amdgcn_update_dpp( \
        (int)(v), (int)(v), (ctrl), 0xf, 0xf, false))

// Full-wave u32 min; uniform result via lane-63 readlane.
__device__ __forceinline__ unsigned int wave_umin_bcast(unsigned int v) {
    v = DPP_UMIN(v, 0x111);   // row_shr:1
    v = DPP_UMIN(v, 0x112);   // row_shr:2
    v = DPP_UMIN(v, 0x114);   // row_shr:4
    v = DPP_UMIN(v, 0x118);   // row_shr:8
    v = DPP_UMIN(v, 0x142);   // row_bcast:15
    v = DPP_UMIN(v, 0x143);   // row_bcast:31
    return (unsigned int)rlanei((int)v, 63);
}

__global__ void zero_out_kernel(float* out, int n) {
    int i = blockIdx.x * blockDim.x + threadIdx.x;
    if (i < n) out[i] = 0.0f;
}

// One wave per batch; lane owns columns/rows {lane, 64+lane, 128+lane, 192+lane}.
// JV: column reduction -> greedy claim -> delta-accumulated Dijkstra searches.
// Register-resident; cross-lane via readlane/DPP. No LDS, no barriers, no ARR
// (R4 showed ARR net-negative on this workload).
__launch_bounds__(64, 1)
__global__ void hungarian_wave(const float* __restrict__ pred,
                               const float* __restrict__ target,
                               float* __restrict__ out) {
    const int b    = blockIdx.x;
    const int lane = threadIdx.x;

    const float* pb = pred   + (size_t)b * NPTS * 3;
    const float* tb = target + (size_t)b * NPTS * 3;

    float prx[4], pry[4], prz[4];      // pred (row) points, row = c*64+lane
    float tx[4], ty[4], tz[4];         // target (col) points, col = c*64+lane
    float vv[4], upc[4], Mv[4];
    float rxc[4], ryc[4], rzc[4];      // matched-row coords, column-attached
    int   pc[4]  = {-1, -1, -1, -1};   // matched row per column (-1 = free)
    int   way[4];
    unsigned int colu[4];              // this lane's column ids

#pragma unroll
    for (int c = 0; c < 4; ++c) {
        int idx = c * 64 + lane;
        prx[c] = pb[idx * 3 + 0]; pry[c] = pb[idx * 3 + 1]; prz[c] = pb[idx * 3 + 2];
        tx[c]  = tb[idx * 3 + 0]; ty[c]  = tb[idx * 3 + 1]; tz[c]  = tb[idx * 3 + 2];
        upc[c] = 0.f; rxc[c] = 0.f; ryc[c] = 0.f; rzc[c] = 0.f;
        colu[c] = (unsigned int)idx;
    }

    // ---- Phase 1a: column reduction. vv[c] = min_r d(r, col), colrow = argmin ----
    float colmin[4] = {BIGF, BIGF, BIGF, BIGF};
    int   colrow[4] = {0, 0, 0, 0};
#pragma unroll
    for (int rs = 0; rs < 4; ++rs) {
        for (int rl = 0; rl < 64; ++rl) {
            float bx = rlane(prx[rs], rl), by = rlane(pry[rs], rl), bz = rlane(prz[rs], rl);
            int r = rs * 64 + rl;
#pragma unroll
            for (int c = 0; c < 4; ++c) {
                float dx = bx - tx[c], dy = by - ty[c], dz = bz - tz[c];
                float d = rawsqrt(dx * dx + dy * dy + dz * dz);
                if (d < colmin[c]) { colmin[c] = d; colrow[c] = r; }
            }
        }
    }
#pragma unroll
    for (int c = 0; c < 4; ++c) vv[c] = colmin[c];

    // ---- Phase 1b: greedy claim — column (ascending) claims its argmin row if free ----
    unsigned long long frm[4];         // free-row masks (wave-uniform values)
    frm[0] = frm[1] = frm[2] = frm[3] = ~0ull;
#pragma unroll
    for (int cs = 0; cs < 4; ++cs) {
        for (int l = 0; l < 64; ++l) {
            int r = rlanei(colrow[cs], l);
            int rs = r >> 6, rl2 = r & 63;
            unsigned long long bit = 1ull << rl2;
            bool free_row = (SEL4(frm, rs) & bit) != 0ull;
            if (free_row) {
#pragma unroll
                for (int s = 0; s < 4; ++s)
                    if (s == rs) frm[s] &= ~bit;
                float bx, by, bz;
                switch (rs) {
                    case 0:  bx = rlane(prx[0], rl2); by = rlane(pry[0], rl2); bz = rlane(prz[0], rl2); break;
                    case 1:  bx = rlane(prx[1], rl2); by = rlane(pry[1], rl2); bz = rlane(prz[1], rl2); break;
                    case 2:  bx = rlane(prx[2], rl2); by = rlane(pry[2], rl2); bz = rlane(prz[2], rl2); break;
                    default: bx = rlane(prx[3], rl2); by = rlane(pry[3], rl2); bz = rlane(prz[3], rl2); break;
                }
                if (lane == l) {
                    pc[cs] = r; upc[cs] = 0.f;
                    rxc[cs] = bx; ryc[cs] = by; rzc[cs] = bz;
                }
            }
        }
    }

    // ---- Phase 2: Dijkstra shortest-path for remaining free rows ----
    float D = 0.f;
#pragma unroll
    for (int is = 0; is < 4; ++is) {
        unsigned long long m = frm[is];
        while (m) {
            const int il = (int)__builtin_ctzll(m);
            m &= (m - 1);
            const int i = is * 64 + il;

            float rootx, rooty, rootz;
            switch (is) {
                case 0:  rootx = rlane(prx[0], il); rooty = rlane(pry[0], il); rootz = rlane(prz[0], il); break;
                case 1:  rootx = rlane(prx[1], il); rooty = rlane(pry[1], il); rootz = rlane(prz[1], il); break;
                case 2:  rootx = rlane(prx[2], il); rooty = rlane(pry[2], il); rootz = rlane(prz[2], il); break;
                default: rootx = rlane(prx[3], il); rooty = rlane(pry[3], il); rootz = rlane(prz[3], il); break;
            }

#pragma unroll
            for (int c = 0; c < 4; ++c) Mv[c] = BIGF;
            int usedm = 0;

            float bx = rootx, by = rooty, bz = rootz;
            float ukey = 0.f;      // u[i0] - D_at_entry
            int j0 = -1;
            int jfin = 0;

            while (true) {
                // t[c] off the sqrt critical path
                float t[4];
#pragma unroll
                for (int c = 0; c < 4; ++c) t[c] = vv[c] + ukey;

                unsigned int kmin = 0xFFFFFFFFu;
#pragma unroll
                for (int c = 0; c < 4; ++c) {
                    float dx = bx - tx[c], dy = by - ty[c], dz = bz - tz[c];
                    float d = rawsqrt(dx * dx + dy * dy + dz * dz);
                    float cand = d - t[c];
                    const bool fr = !((usedm >> c) & 1);
                    if (fr && cand < Mv[c]) { Mv[c] = cand; way[c] = j0; }
                    unsigned int key = fr ? ((__float_as_uint(Mv[c]) & 0xFFFFFF00u) | colu[c])
                                          : 0xFFFFFFFFu;
                    kmin = (min)(kmin, key);
                }
                const unsigned int kk = wave_umin_bcast(kmin);
                const int   j1   = (int)(kk & 0xFFu);
                const float gmin = __uint_as_float(kk & 0xFFFFFF00u);  // truncated value, used consistently
                const int osl = j1 >> 6, oln = j1 & 63;

                // All needed column state in one switch: 5 independent readlanes
                int pj; float uj, nbx, nby, nbz;
                switch (osl) {
                    case 0:  pj = rlanei(pc[0], oln); uj = rlane(upc[0], oln); nbx = rlane(rxc[0], oln); nby = rlane(ryc[0], oln); nbz = rlane(rzc[0], oln); break;
                    case 1:  pj = rlanei(pc[1], oln); uj = rlane(upc[1], oln); nbx = rlane(rxc[1], oln); nby = rlane(ryc[1], oln); nbz = rlane(rzc[1], oln); break;
                    case 2:  pj = rlanei(pc[2], oln); uj = rlane(upc[2], oln); nbx = rlane(rxc[2], oln); nby = rlane(ryc[2], oln); nbz = rlane(rzc[2], oln); break;
                    default: pj = rlanei(pc[3], oln); uj = rlane(upc[3], oln); nbx = rlane(rxc[3], oln); nby = rlane(ryc[3], oln); nbz = rlane(rzc[3], oln); break;
                }
                if (pj < 0) { jfin = j1; D = gmin; break; }

                // Mark used; deferred-dual: +gmin now, net (D - gmin) at commit
#pragma unroll
                for (int c = 0; c < 4; ++c)
                    if (c == osl && lane == oln) {
                        usedm |= (1 << c);
                        vv[c] += gmin;
                        upc[c] -= gmin;
                    }

                bx = nbx; by = nby; bz = nbz;
                ukey = uj - gmin;
                j0 = j1;
            }

            // Commit duals for tree columns: net amount = D_final - D_at_use
#pragma unroll
            for (int c = 0; c < 4; ++c)
                if ((usedm >> c) & 1) { vv[c] -= D; upc[c] += D; }

            // Augment along alternating path (pc + attached u/coords travel together)
            int jc = jfin;
            while (true) {
                const int osl = jc >> 6, oln = jc & 63;
                int jw;
                switch (osl) {
                    case 0:  jw = rlanei(way[0], oln); break;
                    case 1:  jw = rlanei(way[1], oln); break;
                    case 2:  jw = rlanei(way[2], oln); break;
                    default: jw = rlanei(way[3], oln); break;
                }
                int np_; float nup, nrx, nry, nrz;
                if (jw < 0) {   // root: insert row i with u = D_final
                    np_ = i; nup = D; nrx = rootx; nry = rooty; nrz = rootz;
                } else {
                    const int wsl = jw >> 6, wln = jw & 63;
                    switch (wsl) {
                        case 0:  np_ = rlanei(pc[0], wln); nup = rlane(upc[0], wln); nrx = rlane(rxc[0], wln); nry = rlane(ryc[0], wln); nrz = rlane(rzc[0], wln); break;
                        case 1:  np_ = rlanei(pc[1], wln); nup = rlane(upc[1], wln); nrx = rlane(rxc[1], wln); nry = rlane(ryc[1], wln); nrz = rlane(rzc[1], wln); break;
                        case 2:  np_ = rlanei(pc[2], wln); nup = rlane(upc[2], wln); nrx = rlane(rxc[2], wln); nry = rlane(ryc[2], wln); nrz = rlane(rzc[2], wln); break;
                        default: np_ = rlanei(pc[3], wln); nup = rlane(upc[3], wln); nrx = rlane(rxc[3], wln); nry = rlane(ryc[3], wln); nrz = rlane(rzc[3], wln); break;
                    }
                }
#pragma unroll
                for (int c = 0; c < 4; ++c)
                    if (c == osl && lane == oln) {
                        pc[c] = np_; upc[c] = nup;
                        rxc[c] = nrx; ryc[c] = nry; rzc[c] = nrz;
                    }
                if (jw < 0) break;
                jc = jw;
            }
        }
    }

    // ---- Matched cost (coords column-attached; IEEE sqrt here for accuracy) ----
    float s = 0.f;
#pragma unroll
    for (int c = 0; c < 4; ++c) {
        float dx = rxc[c] - tx[c], dy = ryc[c] - ty[c], dz = rzc[c] - tz[c];
        s += sqrtf(dx * dx + dy * dy + dz * dz);
    }
#pragma unroll
    for (int off = 1; off < 64; off <<= 1) s += __shfl_xor(s, off, 64);
    if (lane == 0) atomicAdd(out, s / (float)NBATCH);
}

extern "C" void kernel_launch(void* const* d_in, const int* in_sizes, int n_in,
                              void* d_out, int out_size, void* d_ws, size_t ws_size,
                              hipStream_t stream) {
    const float* pred   = (const float*)d_in[0];
    const float* target = (const float*)d_in[1];
    float* out = (float*)d_out;

    zero_out_kernel<<<1, 64, 0, stream>>>(out, out_size);
    hungarian_wave<<<NBATCH, 64, 0, stream>>>(pred, target, out);
}